// Round 2
// baseline (1169.996 us; speedup 1.0000x reference)
//
#include <hip/hip_runtime.h>

// Problem constants
#define BATCH 256
#define TT 1024
#define IN_DIM 96
#define NU 256
#define NC 10
#define EPS 0.01f
#define BETA 0.5f
#define GAMMA 0.0f
#define TWOLOG2E 2.8853900817779268f   // 2*log2(e): folded into Wa/Esw/Eb

typedef _Float16 f16x8 __attribute__((ext_vector_type(8)));
typedef _Float16 f16x4 __attribute__((ext_vector_type(4)));
typedef float f32x4 __attribute__((ext_vector_type(4)));

// workspace layout (bytes)
// z slab per (t, bb): [w 4][m 16][q 4][16 halfs] = 8KB, u'-permuted unit axis
#define ZP_BYTES ((size_t)TT * 16 * 16 * 256 * 2)       // 134,217,728
#define WSW_OFF  ZP_BYTES
#define WSW_BYTES ((size_t)16384 * 16)                  // 262,144
#define ESW_OFF  (WSW_OFF + WSW_BYTES)

// Unit permutation: orig n = w*64 + i*16 + q*4 + r  <->  u' = w*64 + q*16 + i*4 + r
// (w,i,q,r in 0..3). h LDS, z slab, and W k-axis all use u'; W rows / bias /
// epilogue use orig n.

// ---------------------------------------------------------------------------
// prep_w v9: Wd = EPS*Dm, Wa = (16*2log2e)*A, as swapped-mfma A-operands.
// 4-wave layout: [w 4][mat 2][c 8][i 4][lane 64][8 halfs]. Row n = output unit
// (orig coords); k-element kk = c*32+(l>>4)*8+j indexes u' -> fetch orig unit
// invperm(kk).
__global__ void prep_w(const float* __restrict__ C, const float* __restrict__ B,
                       _Float16* __restrict__ Wsw) {
    int u = blockIdx.x * 256 + threadIdx.x;   // 16384 units
    int l = u & 63;
    int i = (u >> 6) & 3;
    int c = (u >> 8) & 7;
    int mat = (u >> 11) & 1;
    int w = u >> 12;                          // 0..3
    int n = w * 64 + i * 16 + (l & 15);       // output unit (orig)
    int kb = c * 32 + (l >> 4) * 8;
    const float* M = mat ? C : B;             // mat0: Dm from B; mat1: A from C
    float scale = mat ? (16.0f * TWOLOG2E) : EPS;
    f16x8 v;
#pragma unroll
    for (int j = 0; j < 8; j++) {
        int kk = kb + j;                      // u'-coord on contraction axis
        int k = (kk >> 6) * 64 + ((kk >> 2) & 3) * 16
              + ((kk >> 4) & 3) * 4 + (kk & 3);   // invperm -> orig unit
        float m1 = M[k * NU + n];
        float m2 = M[n * NU + k];
        float val = BETA * (m1 - m2) + (1.0f - BETA) * (m1 + m2)
                    - ((k == n) ? GAMMA : 0.0f);
        v[j] = (_Float16)(val * scale);
    }
    ((f16x8*)Wsw)[u] = v;
}

// ---------------------------------------------------------------------------
// prep_e (unchanged layout, 2log2e-scaled): [w 4][c 3][i 4][lane 64][8 halfs]
__global__ void prep_e(const float* __restrict__ Ew, _Float16* __restrict__ Esw) {
    int u = blockIdx.x * 256 + threadIdx.x;   // 3072 units
    int l = u & 63;
    int i = (u >> 6) & 3;
    int wc = u >> 8;
    int c = wc % 3;
    int w = wc / 3;
    int n = w * 64 + i * 16 + (l & 15);
    int kb = c * 32 + (l >> 4) * 8;
    f16x8 v;
#pragma unroll
    for (int j = 0; j < 8; j++)
        v[j] = (_Float16)(Ew[n * IN_DIM + kb + j] * TWOLOG2E);
    ((f16x8*)Esw)[u] = v;
}

// ---------------------------------------------------------------------------
// zproj v9: no LDS, no barriers. Swapped mfma -> lane(m,q) of wave wz holds
// D[unit wz*64+i4*16+q*4+r][batch m]. Store directly into the u'-permuted
// slab: offset = ((wz*16+m)*4+q)*16 + i4*4 + r -> two contiguous 16B stores.
__global__ __launch_bounds__(256) void zproj(const float* __restrict__ x,
                                             const float* __restrict__ Eb,
                                             const _Float16* __restrict__ Esw,
                                             _Float16* __restrict__ zp) {
    int tid = threadIdx.x;
    int l = tid & 63, wz = tid >> 6, m = l & 15, q = l >> 4;
    int bb = blockIdx.x & 15, tb = blockIdx.x >> 4;
    int t0 = tb * 16, B0 = bb * 16;

    f16x8 ef[3][4];
    const f16x8* Ep = (const f16x8*)Esw;
#pragma unroll
    for (int c = 0; c < 3; c++)
#pragma unroll
        for (int i = 0; i < 4; i++)
            ef[c][i] = Ep[((wz * 3 + c) * 4 + i) * 64 + l];
    // bias per output unit (orig coords): wz*64 + i*16 + q*4 + r (scaled)
    f32x4 ebv[4];
#pragma unroll
    for (int i = 0; i < 4; i++) {
        float4 b4 = *(const float4*)&Eb[wz * 64 + i * 16 + q * 4];
        f32x4 e4 = {b4.x * TWOLOG2E, b4.y * TWOLOG2E,
                    b4.z * TWOLOG2E, b4.w * TWOLOG2E};
        ebv[i] = e4;
    }

    const float* xbase = x + (size_t)(B0 + m) * TT * IN_DIM + q * 8;

    for (int t = 0; t < 16; t++) {
        f16x8 af[3];
#pragma unroll
        for (int c = 0; c < 3; c++) {
            const float* px = xbase + (size_t)(t0 + t) * IN_DIM + c * 32;
            float4 v0 = *(const float4*)px;
            float4 v1 = *(const float4*)(px + 4);
            f16x8 a;
            a[0] = (_Float16)v0.x; a[1] = (_Float16)v0.y;
            a[2] = (_Float16)v0.z; a[3] = (_Float16)v0.w;
            a[4] = (_Float16)v1.x; a[5] = (_Float16)v1.y;
            a[6] = (_Float16)v1.z; a[7] = (_Float16)v1.w;
            af[c] = a;
        }
        f32x4 acc[4];
#pragma unroll
        for (int i = 0; i < 4; i++) acc[i] = ebv[i];
#pragma unroll
        for (int c = 0; c < 3; c++)
#pragma unroll
            for (int i = 0; i < 4; i++)
                acc[i] = __builtin_amdgcn_mfma_f32_16x16x32_f16(ef[c][i], af[c], acc[i], 0, 0, 0);

        f16x8 o0, o1;
#pragma unroll
        for (int r = 0; r < 4; r++) {
            o0[r]     = (_Float16)acc[0][r];
            o0[4 + r] = (_Float16)acc[1][r];
            o1[r]     = (_Float16)acc[2][r];
            o1[4 + r] = (_Float16)acc[3][r];
        }
        _Float16* dst = zp + (((size_t)(t0 + t) * 16 + bb) * 4096)
                        + ((size_t)((wz * 16 + m) * 4 + q)) * 16;
        *(f16x8*)dst = o0;
        *(f16x8*)(dst + 8) = o1;
    }
}

// ---------------------------------------------------------------------------
// Recurrence v9: 4 waves x 64 units (halves redundant LDS h-reads: 32 b128
// per WG-step instead of 64). Weights 2 mats x 8c x 4i = 64 f16x8 resident.
// h' write = 2 contiguous b128 (u'-permuted columns). Raw s_barrier +
// lgkmcnt(0) only: z prefetch global loads stay in flight across barriers.

__device__ __forceinline__ void load_z2(f16x8 zc[2][2],
                                        const _Float16* __restrict__ zp,
                                        int tb, int wg, size_t voff) {
#pragma unroll
    for (int s = 0; s < 2; s++) {
        int ts = tb + s; ts = (ts > TT - 1) ? TT - 1 : ts;
        const _Float16* pz = zp + ((size_t)ts * 16 + wg) * 4096 + voff;
        zc[s][0] = *(const f16x8*)pz;
        zc[s][1] = *(const f16x8*)(pz + 8);
    }
}

__device__ __forceinline__ void step_fn(const _Float16* __restrict__ hb,
                                        _Float16* __restrict__ hn,
                                        const f16x8 wd[8][4], const f16x8 wa[8][4],
                                        float hm[16], const f16x8 zs[2],
                                        int m, int q, int w) {
    f32x4 faccD[4], faccA[4];
    f32x4 dinit = {EPS * 0.0625f, EPS * 0.0625f, EPS * 0.0625f, EPS * 0.0625f};
#pragma unroll
    for (int i = 0; i < 4; i++) {
        faccD[i] = dinit;                      // +EPS/16 folded in
        f32x4 zi = {(float)zs[i >> 1][(i & 1) * 4 + 0],
                    (float)zs[i >> 1][(i & 1) * 4 + 1],
                    (float)zs[i >> 1][(i & 1) * 4 + 2],
                    (float)zs[i >> 1][(i & 1) * 4 + 3]};
        faccA[i] = zi;                         // z (pre-scaled by 2log2e)
    }

#pragma unroll
    for (int c = 0; c < 8; c++) {
        f16x8 af = *(const f16x8*)&hb[m * 264 + c * 32 + q * 8];
#pragma unroll
        for (int i = 0; i < 4; i++) {
            faccD[i] = __builtin_amdgcn_mfma_f32_16x16x32_f16(wd[c][i], af, faccD[i], 0, 0, 0);
            faccA[i] = __builtin_amdgcn_mfma_f32_16x16x32_f16(wa[c][i], af, faccA[i], 0, 0, 0);
        }
    }

    f16x8 o0, o1;
#pragma unroll
    for (int i = 0; i < 4; i++) {
#pragma unroll
        for (int r = 0; r < 4; r++) {
            float e = __builtin_amdgcn_exp2f(faccA[i][r]);   // 2^(2log2e*(hA+z))
            float R = __builtin_amdgcn_rcpf(e + 1.0f);
            float s = hm[i * 4 + r] + faccD[i][r];
            hm[i * 4 + r] = s - (2.0f * EPS * 0.0625f) * R;
            _Float16 hv = (_Float16)hm[i * 4 + r];           // h' = h/16
            if (i < 2) o0[(i & 1) * 4 + r] = hv;
            else       o1[(i & 1) * 4 + r] = hv;
        }
    }
    _Float16* dst = &hn[m * 264 + w * 64 + q * 16];
    *(f16x8*)dst = o0;                          // u'-contiguous: 2x b128
    *(f16x8*)(dst + 8) = o1;

    asm volatile("s_waitcnt lgkmcnt(0)" ::: "memory");  // drain LDS only
    __builtin_amdgcn_s_barrier();                        // NO vmcnt drain
    __builtin_amdgcn_sched_barrier(0);                   // fence reordering
}

__global__ __launch_bounds__(256, 1) void recur(const _Float16* __restrict__ Wsw,
                                                const _Float16* __restrict__ zp,
                                                const float* __restrict__ Dw,
                                                const float* __restrict__ Db,
                                                float* __restrict__ out) {
    __shared__ __align__(16) _Float16 hbuf0[16 * 264];
    __shared__ __align__(16) _Float16 hbuf1[16 * 264];
    __shared__ float Yep[16 * 257];
    int tid = threadIdx.x;
    int l = tid & 63, w = tid >> 6, m = l & 15, q = l >> 4;
    int wg = blockIdx.x;

    // resident weight fragments: 64 f16x8 = 256 regs (AGPR-parked)
    f16x8 wd[8][4], wa[8][4];
    const f16x8* Wp = (const f16x8*)Wsw;
#pragma unroll
    for (int c = 0; c < 8; c++)
#pragma unroll
        for (int i = 0; i < 4; i++) {
            wd[c][i] = Wp[(((w * 2 + 0) * 8 + c) * 4 + i) * 64 + l];
            wa[c][i] = Wp[(((w * 2 + 1) * 8 + c) * 4 + i) * 64 + l];
        }
#pragma unroll
    for (int c = 0; c < 8; c++)
#pragma unroll
        for (int i = 0; i < 4; i++)
            asm volatile("" : "+v"(wd[c][i]), "+v"(wa[c][i]));

    float hm[16];
#pragma unroll
    for (int e = 0; e < 16; e++) hm[e] = 0.0f;
    for (int idx = tid; idx < 16 * 264; idx += 256) hbuf0[idx] = (_Float16)0.0f;

    // z offset within (t, wg) slab [w 4][m 16][q 4][16 halfs]
    size_t voff = (size_t)((w * 16 + m) * 4 + q) * 16;
    f16x8 zA[2][2], zB[2][2];
    load_z2(zA, zp, 0, wg, voff);
    load_z2(zB, zp, 2, wg, voff);
    __syncthreads();

    for (int t = 0; t < TT; t += 4) {
        step_fn(hbuf0, hbuf1, wd, wa, hm, zA[0], m, q, w);
        step_fn(hbuf1, hbuf0, wd, wa, hm, zA[1], m, q, w);
        load_z2(zA, zp, t + 4, wg, voff);
        step_fn(hbuf0, hbuf1, wd, wa, hm, zB[0], m, q, w);
        step_fn(hbuf1, hbuf0, wd, wa, hm, zB[1], m, q, w);
        load_z2(zB, zp, t + 6, wg, voff);
    }

    // epilogue: out[b][c] = h[b][:] @ Dw[c][:] + Db[c]   (h = 16*hm')
    // lane(m,q,w) holds batch m, orig units w*64 + i*16 + q*4 + r
#pragma unroll
    for (int i = 0; i < 4; i++)
#pragma unroll
        for (int r = 0; r < 4; r++)
            Yep[m * 257 + w * 64 + i * 16 + q * 4 + r] = 16.0f * hm[i * 4 + r];
    __syncthreads();
    if (tid < 160) {
        int rr = tid / 10, c = tid - rr * 10;
        float s = Db[c];
        for (int k = 0; k < 256; k++) s += Yep[rr * 257 + k] * Dw[c * 256 + k];
        out[(wg * 16 + rr) * 10 + c] = s;
    }
}

// ---------------------------------------------------------------------------
extern "C" void kernel_launch(void* const* d_in, const int* in_sizes, int n_in,
                              void* d_out, int out_size, void* d_ws, size_t ws_size,
                              hipStream_t stream) {
    const float* x  = (const float*)d_in[0];
    const float* Ew = (const float*)d_in[1];
    const float* Eb = (const float*)d_in[2];
    const float* C  = (const float*)d_in[3];
    const float* B  = (const float*)d_in[4];
    const float* Dw = (const float*)d_in[5];
    const float* Db = (const float*)d_in[6];
    float* out = (float*)d_out;

    char* ws = (char*)d_ws;
    _Float16* zp  = (_Float16*)(ws);
    _Float16* Wsw = (_Float16*)(ws + WSW_OFF);
    _Float16* Esw = (_Float16*)(ws + ESW_OFF);

    hipLaunchKernelGGL(prep_w, dim3(64), dim3(256), 0, stream, C, B, Wsw);
    hipLaunchKernelGGL(prep_e, dim3(12), dim3(256), 0, stream, Ew, Esw);
    hipLaunchKernelGGL(zproj, dim3(1024), dim3(256), 0, stream, x, Eb, Esw, zp);
    hipLaunchKernelGGL(recur, dim3(16), dim3(256), 0, stream, Wsw, zp, Dw, Db, out);
}